// Round 9
// baseline (1728.928 us; speedup 1.0000x reference)
//
#include <hip/hip_runtime.h>
#include <math.h>

#define N_NODES 50000
#define N_EDGES 800000
#define SCAN_B 512
#define SCAN_NBLK ((N_NODES + SCAN_B - 1) / SCAN_B)   // 98

typedef unsigned short u16;
typedef unsigned int u32;
typedef _Float16 f16;
typedef __fp16 h2 __attribute__((ext_vector_type(2)));   // matches cvt_pkrtz / fdot2
typedef _Float16 v8h __attribute__((ext_vector_type(8))); // MFMA A/B fragment
typedef float v4f __attribute__((ext_vector_type(4)));    // MFMA C/D fragment

union U32H2 { u32 u; h2 h; };
__device__ __forceinline__ h2 u2h(u32 x) { U32H2 t; t.u = x; return t.h; }
__device__ __forceinline__ u32 h2u(h2 x) { U32H2 t; t.h = x; return t.u; }

union V8U { v8h v; u32 u[4]; };

// DPP cross-lane move (VALU pipe). Rotation-reduce within 16-row.
template<int CTRL>
__device__ __forceinline__ h2 dppmov(h2 x) {
    return u2h((u32)__builtin_amdgcn_update_dpp(0, (int)h2u(x), CTRL, 0xF, 0xF, true));
}
__device__ __forceinline__ h2 swz16(h2 x) {   // lane ^= 16 within each 32-group
    return u2h((u32)__builtin_amdgcn_ds_swizzle((int)h2u(x), 0x401F));
}

// ---------------- K-1: degree count ----------------
__global__ void k_deg(const int* __restrict__ dst, int* __restrict__ deg) {
    int e = blockIdx.x * blockDim.x + threadIdx.x;
    if (e < N_EDGES) atomicAdd(&deg[dst[e]], 1);
}

// ---------------- K-0.5: pack raw features f16 [n][96] (x 32 | h 64) -------
// Round 9: the gat kernel gathers 192 B of RAW features per edge instead of
// the 1 KB precomputed XL row (8 -> ~1.7 cache lines per edge), and
// recomputes xl via MFMA. This is the line-count cut the invariant demands.
__global__ void k_pack_raw(const float* __restrict__ x_t,
                           const float* __restrict__ h_prev,
                           f16* __restrict__ raw16) {
    int t = blockIdx.x * blockDim.x + threadIdx.x;
    if (t >= N_NODES * 96) return;
    int q = t >> 5;                                             // t/32
    int n = (int)(((unsigned long long)q * 0xAAAAAAABull) >> 33); // q/3 -> t/96
    int e = t - n * 96;
    float v = (e < 32) ? x_t[n * 32 + e] : h_prev[(size_t)n * 64 + (e - 32)];
    raw16[t] = (f16)v;
}

// ---------------- K1: XR node features (lin_r) PAIR-MAJOR f16 --------------
// Layout: [n][pr(4)][c(64)][i(2)]. 256 threads = 4 waves, wave g -> inst g.
template<int K>
__global__ void __launch_bounds__(256)
k_node_feats_r(const float* __restrict__ in,
               const float* __restrict__ Wr, const float* __restrict__ br,
               f16* __restrict__ XRt, int inst_base) {
    int w = threadIdx.x >> 6;
    int c = threadIdx.x & 63;
    int g = w;
    int inst = inst_base + g;
    size_t ooff = (size_t)(inst >> 1) * 128 + (size_t)c * 2 + (inst & 1);
    float wcol[K];
    #pragma unroll
    for (int k = 0; k < K; k++) wcol[k] = Wr[(g*K + k)*64 + c];
    float b = br[g*64 + c];
    for (int n = blockIdx.x; n < N_NODES; n += gridDim.x) {
        const float* row = in + (size_t)n * K;   // wave-uniform -> scalar loads
        float acc = b;
        #pragma unroll
        for (int k = 0; k < K; k++) acc = fmaf(row[k], wcol[k], acc);
        XRt[(size_t)n * 512 + ooff] = (f16)acc;
    }
}

// ---------------- K2: CSR build (scan) ----------------
__global__ void __launch_bounds__(SCAN_B)
k_scan1(const int* __restrict__ deg, int* __restrict__ tmp, int* __restrict__ partials) {
    __shared__ int s[SCAN_B];
    int t = threadIdx.x;
    int i = blockIdx.x * SCAN_B + t;
    int v = (i < N_NODES) ? deg[i] : 0;
    s[t] = v;
    __syncthreads();
    #pragma unroll
    for (int off = 1; off < SCAN_B; off <<= 1) {
        int add = (t >= off) ? s[t - off] : 0;
        __syncthreads();
        s[t] += add;
        __syncthreads();
    }
    if (i < N_NODES) tmp[i] = s[t];
    if (t == SCAN_B - 1) partials[blockIdx.x] = s[SCAN_B - 1];
}

__global__ void __launch_bounds__(64)
k_scan2(int* __restrict__ partials) {
    int lane = threadIdx.x;
    int carry = 0;
    for (int base = 0; base < SCAN_NBLK; base += 64) {
        int i = base + lane;
        int v = (i < SCAN_NBLK) ? partials[i] : 0;
        #pragma unroll
        for (int off = 1; off < 64; off <<= 1) {
            int u = __shfl_up(v, off);
            if (lane >= off) v += u;
        }
        if (i < SCAN_NBLK) partials[i] = v + carry;
        carry += __shfl(v, 63);
    }
}

__global__ void __launch_bounds__(SCAN_B)
k_scan3(const int* __restrict__ tmp, const int* __restrict__ partials,
        int* __restrict__ row_ptr, int* __restrict__ cursor) {
    int i = blockIdx.x * SCAN_B + threadIdx.x;
    if (i < N_NODES) {
        int b = blockIdx.x;
        int off = (b > 0) ? partials[b - 1] : 0;
        row_ptr[i + 1] = off + tmp[i];
        cursor[i] = 0;
        if (i == 0) row_ptr[0] = 0;
    }
}

// ---------------- K0: edge MLP scattered to CSR slot -----------------------
// sorted_soff now stores src*192 (byte offset into raw16).
__global__ void k_edge_mlp_scatter(const float* __restrict__ edge_attr,
                                   const float* __restrict__ Wm1, const float* __restrict__ bm1,
                                   const float* __restrict__ Wm2, const float* __restrict__ bm2,
                                   const int* __restrict__ src, const int* __restrict__ dst,
                                   const int* __restrict__ row_ptr, int* __restrict__ cursor,
                                   f16* __restrict__ sorted_e, int* __restrict__ sorted_soff) {
    int e = blockIdx.x * blockDim.x + threadIdx.x;
    if (e >= N_EDGES) return;
    const float4* ap = (const float4*)(edge_attr + (size_t)e * 16);
    float a[16];
    #pragma unroll
    for (int i = 0; i < 4; i++) {
        float4 r = ap[i];
        a[4*i] = r.x; a[4*i+1] = r.y; a[4*i+2] = r.z; a[4*i+3] = r.w;
    }
    float g1[16];
    #pragma unroll
    for (int j = 0; j < 16; j++) {
        float v = bm1[j];
        #pragma unroll
        for (int k = 0; k < 16; k++) v = fmaf(a[k], Wm1[k*16 + j], v);
        g1[j] = 0.5f * v * (1.0f + erff(v * 0.70710678118654752f));
    }
    float o[16];
    #pragma unroll
    for (int j = 0; j < 16; j++) {
        float v = bm2[j];
        #pragma unroll
        for (int k = 0; k < 16; k++) v = fmaf(g1[k], Wm2[k*16 + j], v);
        o[j] = v;
    }
    u32 w[8];
    #pragma unroll
    for (int k2 = 0; k2 < 8; k2++) w[k2] = h2u(__builtin_amdgcn_cvt_pkrtz(o[2*k2], o[2*k2+1]));
    int d = dst[e];
    int pos = row_ptr[d] + atomicAdd(&cursor[d], 1);
    uint4* op = (uint4*)(sorted_e + (size_t)pos * 16);
    op[0] = make_uint4(w[0], w[1], w[2], w[3]);
    op[1] = make_uint4(w[4], w[5], w[6], w[7]);
    sorted_soff[pos] = src[e] * 192;       // raw16 row byte offset
}

// ---------------- K3: fused GATv2 x8 + LSTM + LayerNorm ----------------
// Round 9: RAW-GATHER + MFMA xl-recompute. Per 32-edge chunk:
//   1. all 256 threads gather the 32 raw rows (192B each) into LDS
//   2. each wave recomputes xl for its 2 insts via mfma_f32_16x16x32_f16
//      (C-init = lin_l bias broadcast; D rows=edges, cols=channels) and
//      packs (i0,i1) h2 words into its private xl_lds slice
//   3. round-8 per-edge machinery unchanged, xl served from LDS.
// Gathered bytes/edge: 1024 -> 192 (8 -> ~1.7 lines): the line-throughput
// wall (1 line/~40cyc/CU, from rounds 3-8 invariance) predicts ~2x+.
__global__ void __launch_bounds__(256) __attribute__((amdgpu_waves_per_eu(1, 2)))
k_gat_main(const f16* __restrict__ sorted_e,
           const int* __restrict__ sorted_soff,
           const f16* __restrict__ raw16,
           const f16* __restrict__ XRt,
           const int* __restrict__ row_ptr,
           const float* __restrict__ Wlx, const float* __restrict__ blx,
           const float* __restrict__ Wlh, const float* __restrict__ blh,
           const float* __restrict__ Wex, const float* __restrict__ Weh,
           const float* __restrict__ attx, const float* __restrict__ atth,
           const float* __restrict__ biasx, const float* __restrict__ biash,
           const float* __restrict__ c_prev,
           const float* __restrict__ ln_g, const float* __restrict__ ln_b,
           float* __restrict__ out) {
    int tid = threadIdx.x;
    int wv = tid >> 6;
    int lane = tid & 63;
    int n = blockIdx.x;                   // one node per block
    int c = lane;
    int hh = c >> 5;
    int ch = c & 31;
    int i0 = 2 * wv, i1 = 2 * wv + 1;
    bool isX = (wv < 2);
    int g0 = isX ? i0 : (i0 - 4);         // first gate index within Wl tensor
    const int K = isX ? 32 : 64;
    const float* Wl = isX ? Wlx : Wlh;
    const float* bl = isX ? blx : blh;
    int lg = lane >> 4;                   // lane group (0..3)
    int ll = lane & 15;

    __shared__ u32 wlds[8 * 8 * 64];      // ee weights, 16 KB
    __shared__ float glds[8][64];         // gate exchange, 2 KB
    __shared__ int soff_lds[32];
    __shared__ uint4 raw_lds4[384];       // 32 edges x 192 B = 6 KB
    __shared__ u32 xl_lds[4][32][64];     // per-wave xl slices, 32 KB

    // Stage packed We columns (ee weights) in LDS, as in round 8
    {
        #pragma unroll
        for (int it = 0; it < 16; it++) {
            int idx = it * 256 + tid;
            int inst = idx >> 9;
            int k2 = (idx >> 6) & 7;
            int cc = idx & 63;
            const float* Wsrc = (inst < 4)
                ? (Wex + ((inst * 16 + 2 * k2) * 64 + cc))
                : (Weh + (((inst - 4) * 16 + 2 * k2) * 64 + cc));
            wlds[idx] = h2u(__builtin_amdgcn_cvt_pkrtz(Wsrc[0], Wsrc[64]));
        }
    }
    __syncthreads();

    // att for this wave's instance pair
    h2 attp;
    {
        float a0 = (i0 < 4) ? attx[(i0*2 + hh)*32 + ch] : atth[((i0-4)*2 + hh)*32 + ch];
        float a1 = (i1 < 4) ? attx[(i1*2 + hh)*32 + ch] : atth[((i1-4)*2 + hh)*32 + ch];
        attp = __builtin_amdgcn_cvt_pkrtz(a0, a1);
    }
    // ee We columns for this wave's 2 insts (16 VGPRs)
    h2 wef[2][8];
    #pragma unroll
    for (int ii = 0; ii < 2; ii++) {
        #pragma unroll
        for (int k2 = 0; k2 < 8; k2++)
            wef[ii][k2] = u2h(wlds[((i0 + ii) * 8 + k2) * 64 + c]);
    }
    // xr dword (pair-major XRt, coalesced)
    h2 xrp;
    {
        u32 rx = *(const u32*)((const char*)XRt + (size_t)n*1024 + (wv << 8) + (c << 2));
        xrp = u2h(rx);
    }

    // B fragments + bias for the xl-recompute MFMA.
    // B[nt][ks]: nt 0-3 -> inst i0 channels nt*16+ll; nt 4-7 -> inst i1.
    // frag element j (0..7) = W[k = ks*32 + lg*8 + j][channel].
    V8U Bf[8][2];
    float biasD[8];
    int nks = K >> 5;
    #pragma unroll
    for (int nt = 0; nt < 8; nt++) {
        int ga = g0 + (nt >> 2);
        int cc = (nt & 3) * 16 + ll;
        biasD[nt] = bl[ga * 64 + cc];
        for (int ks = 0; ks < nks; ks++) {
            #pragma unroll
            for (int p = 0; p < 4; p++) {
                float w0 = Wl[(ga*K + ks*32 + lg*8 + 2*p    ) * 64 + cc];
                float w1 = Wl[(ga*K + ks*32 + lg*8 + 2*p + 1) * 64 + cc];
                Bf[nt][ks].u[p] = h2u(__builtin_amdgcn_cvt_pkrtz(w0, w1));
            }
        }
    }

    h2 accp = (h2)0, denp = (h2)0;
    const char* seb = (const char*)sorted_e;
    const char* rawb = (const char*)raw16;

    int start = row_ptr[n];
    int end = row_ptr[n + 1];
    for (int base = start; base < end; base += 32) {
        int rem = end - base;
        int cnt = rem < 32 ? rem : 32;

        // stage soff (every wave writes its own identical copy -> intra-wave dep only)
        if (lane < 32) {
            int idx = base + lane;
            soff_lds[lane] = (idx < end) ? sorted_soff[idx] : 0;
        }
        // cooperative raw gather: 384 16B frags; frag f -> edge f/12, sub f%12
        {
            int f0 = tid;
            int e0 = (f0 * 2731) >> 15;          // exact /12 for f<384
            int fr0 = f0 - e0 * 12;
            raw_lds4[f0] = *(const uint4*)(rawb + soff_lds[e0] + fr0 * 16);
            if (tid < 128) {
                int f1 = tid + 256;
                int e1 = (f1 * 2731) >> 15;
                int fr1 = f1 - e1 * 12;
                raw_lds4[f1] = *(const uint4*)(rawb + soff_lds[e1] + fr1 * 16);
            }
        }
        // er chunk load: lane owns edge (base+lane)'s 32B e-row (pad covers tail)
        uint4 er0, er1;
        {
            const uint4* erp = (const uint4*)(seb + (size_t)(base + lane) * 32);
            er0 = erp[0]; er1 = erp[1];
        }
        __syncthreads();   // raw_lds ready (full drain)

        // ---- MFMA pre-phase: xl[32e][128c] for this wave's 2 insts ----
        {
            v4f D[2][8];
            #pragma unroll
            for (int mt = 0; mt < 2; mt++)
                #pragma unroll
                for (int nt = 0; nt < 8; nt++) {
                    float b = biasD[nt];
                    D[mt][nt] = (v4f){b, b, b, b};
                }
            const char* rl = (const char*)raw_lds4;
            int srcoff = isX ? 0 : 64;    // x at [0,64), h at [64,192) of each row
            for (int ks = 0; ks < nks; ks++) {
                #pragma unroll
                for (int mt = 0; mt < 2; mt++) {
                    int rowbyte = (mt * 16 + ll) * 192 + srcoff + ks * 64 + lg * 16;
                    v8h A = *(const v8h*)(rl + rowbyte);
                    #pragma unroll
                    for (int nt = 0; nt < 8; nt++)
                        D[mt][nt] = __builtin_amdgcn_mfma_f32_16x16x32_f16(
                            A, Bf[nt][ks].v, D[mt][nt], 0, 0, 0);
                }
            }
            // pack (i0,i1) per channel and store to this wave's xl slice.
            // D layout: col = ll (channel within tile), row = lg*4 + r (edge).
            #pragma unroll
            for (int mt = 0; mt < 2; mt++)
                #pragma unroll
                for (int nt = 0; nt < 4; nt++)
                    #pragma unroll
                    for (int r = 0; r < 4; r++) {
                        u32 w = h2u(__builtin_amdgcn_cvt_pkrtz(D[mt][nt][r], D[mt][nt + 4][r]));
                        int e = mt * 16 + lg * 4 + r;
                        xl_lds[wv][e][nt * 16 + ll] = w;
                    }
        }
        __syncthreads();   // raw_lds reads done before next chunk's gather

        // ---- main per-edge loop (round-8 machinery, xl from LDS) ----
        for (int j = 0; j < cnt; j++) {
            h2 es[8] = {
                u2h((u32)__builtin_amdgcn_readlane((int)er0.x, j)),
                u2h((u32)__builtin_amdgcn_readlane((int)er0.y, j)),
                u2h((u32)__builtin_amdgcn_readlane((int)er0.z, j)),
                u2h((u32)__builtin_amdgcn_readlane((int)er0.w, j)),
                u2h((u32)__builtin_amdgcn_readlane((int)er1.x, j)),
                u2h((u32)__builtin_amdgcn_readlane((int)er1.y, j)),
                u2h((u32)__builtin_amdgcn_readlane((int)er1.z, j)),
                u2h((u32)__builtin_amdgcn_readlane((int)er1.w, j))
            };
            h2 xlp = u2h(xl_lds[wv][j][c]);
            h2 s = xlp + xrp;              // v_pk_add_f16
            float m0 = (float)s[0];
            float m1 = (float)s[1];
            #pragma unroll
            for (int k2 = 0; k2 < 8; k2++) {
                m0 = __builtin_amdgcn_fdot2(es[k2], wef[0][k2], m0, false);
                m1 = __builtin_amdgcn_fdot2(es[k2], wef[1][k2], m1, false);
            }
            h2 mm = __builtin_amdgcn_cvt_pkrtz(m0, m1);
            h2 mr = __builtin_elementwise_max(mm, mm * (h2)0.2f16);  // leaky_relu
            h2 tp = mr * attp;
            tp = tp + dppmov<0xB1>(tp);
            tp = tp + dppmov<0x4E>(tp);
            tp = tp + dppmov<0x124>(tp);
            tp = tp + dppmov<0x128>(tp);
            tp = tp + swz16(tp);
            float p0 = __expf((float)tp[0]);
            float p1 = __expf((float)tp[1]);
            h2 pp = __builtin_amdgcn_cvt_pkrtz(p0, p1);
            denp = denp + pp;
            accp = __builtin_elementwise_fma(pp, xlp, accp);
        }
    }

    // per-wave gate contribution -> LDS
    {
        float b0 = (i0 < 4) ? biasx[i0*64 + c] : biash[(i0-4)*64 + c];
        float b1 = (i1 < 4) ? biasx[i1*64 + c] : biash[(i1-4)*64 + c];
        float v0 = (float)accp[0] / ((float)denp[0] + 1e-16f) + b0;
        float v1 = (float)accp[1] / ((float)denp[1] + 1e-16f) + b1;
        glds[i0][c] = v0;
        glds[i1][c] = v1;
    }
    __syncthreads();
    if (wv != 0) return;

    float gates[4];
    #pragma unroll
    for (int g = 0; g < 4; g++) gates[g] = glds[g][c] + glds[4 + g][c];
    float it = 1.f / (1.f + __expf(-gates[0]));
    float ft = 1.f / (1.f + __expf(-gates[1]));
    float ot = 1.f / (1.f + __expf(-gates[2]));
    float gt = tanhf(gates[3]);
    float cp = c_prev[(size_t)n*64 + c];
    float ct = ft * cp + it * gt;
    float ht = ot * tanhf(ct);
    float s1 = ht;
    #pragma unroll
    for (int off = 32; off >= 1; off >>= 1) s1 += __shfl_xor(s1, off);
    float mu = s1 * (1.f / 64.f);
    float d = ht - mu;
    float s2 = d * d;
    #pragma unroll
    for (int off = 32; off >= 1; off >>= 1) s2 += __shfl_xor(s2, off);
    float var = s2 * (1.f / 64.f);
    float y = d * rsqrtf(var + 1e-5f) * ln_g[c] + ln_b[c];
    out[(size_t)n*64 + c] = y;
    out[(size_t)(N_NODES + n)*64 + c] = ct;
}

extern "C" void kernel_launch(void* const* d_in, const int* in_sizes, int n_in,
                              void* d_out, int out_size, void* d_ws, size_t ws_size,
                              hipStream_t stream) {
    const float* x_t    = (const float*)d_in[0];
    const float* h_prev = (const float*)d_in[1];
    const float* c_prev = (const float*)d_in[2];
    const int*   ei     = (const int*)d_in[3];
    const float* eattr  = (const float*)d_in[4];
    const float* Wm1    = (const float*)d_in[5];
    const float* bm1    = (const float*)d_in[6];
    const float* Wm2    = (const float*)d_in[7];
    const float* bm2    = (const float*)d_in[8];
    const float* Wlx    = (const float*)d_in[9];
    const float* blx    = (const float*)d_in[10];
    const float* Wrx    = (const float*)d_in[11];
    const float* brx    = (const float*)d_in[12];
    const float* Wex    = (const float*)d_in[13];
    const float* attx   = (const float*)d_in[14];
    const float* biasx  = (const float*)d_in[15];
    const float* Wlh    = (const float*)d_in[16];
    const float* blh    = (const float*)d_in[17];
    const float* Wrh    = (const float*)d_in[18];
    const float* brh    = (const float*)d_in[19];
    const float* Weh    = (const float*)d_in[20];
    const float* atth   = (const float*)d_in[21];
    const float* biash  = (const float*)d_in[22];
    const float* ln_g   = (const float*)d_in[23];
    const float* ln_b   = (const float*)d_in[24];

    char* ws = (char*)d_ws;
    f16*   XRt      = (f16*)(ws + 0);             // 51,200,000 B
    f16*   raw16    = (f16*)(ws + 51200000);      //  9,600,000 B (+12,288 pad)
    f16*   sorted_e = (f16*)(ws + 60812288);      // 25,602,048 B (800064 rows x 32 B)
    int*   sorted_soff = (int*)(ws + 86414336);   //  3,200,256 B
    int*   row_ptr  = (int*)(ws + 89614592);      //    200,704 B
    int*   degcur   = (int*)(ws + 89815296);      //    200,704 B
    int*   scan_tmp = (int*)(ws + 90016000);      //    204,800 B
    int*   partials = (int*)(ws + 90220800);      //        512 B

    const int* srcp = ei;
    const int* dstp = ei + N_EDGES;

    (void)hipMemsetAsync(degcur, 0, N_NODES * sizeof(int), stream);

    k_deg<<<(N_EDGES + 255) / 256, 256, 0, stream>>>(dstp, degcur);
    k_pack_raw<<<(N_NODES * 96 + 255) / 256, 256, 0, stream>>>(x_t, h_prev, raw16);
    k_node_feats_r<32><<<6250, 256, 0, stream>>>(x_t, Wrx, brx, XRt, 0);
    k_node_feats_r<64><<<6250, 256, 0, stream>>>(h_prev, Wrh, brh, XRt, 4);
    k_scan1<<<SCAN_NBLK, SCAN_B, 0, stream>>>(degcur, scan_tmp, partials);
    k_scan2<<<1, 64, 0, stream>>>(partials);
    k_scan3<<<SCAN_NBLK, SCAN_B, 0, stream>>>(scan_tmp, partials, row_ptr, degcur);
    k_edge_mlp_scatter<<<(N_EDGES + 255) / 256, 256, 0, stream>>>(
        eattr, Wm1, bm1, Wm2, bm2, srcp, dstp, row_ptr, degcur, sorted_e, sorted_soff);
    k_gat_main<<<N_NODES, 256, 0, stream>>>(sorted_e, sorted_soff, raw16, XRt, row_ptr,
                                            Wlx, blx, Wlh, blh, Wex, Weh,
                                            attx, atth, biasx, biash,
                                            c_prev, ln_g, ln_b, (float*)d_out);
}